// Round 5
// baseline (3090.160 us; speedup 1.0000x reference)
//
#include <hip/hip_runtime.h>
#include <cstdint>

typedef unsigned u32t;
typedef unsigned long long u64;
typedef float f32x4 __attribute__((ext_vector_type(4)));
typedef short s16x4 __attribute__((ext_vector_type(4)));

#define Qn   515
#define QP   520          // padded cols of A
#define Bn   256
#define Tn   512
#define OQ   516
#define EPSc 1e-16f
#define NSL  65           // real cols per block slice
#define NT   5            // 16-wide n tiles per slice
#define KT   33           // k tiles over padded k space (528/16)
#define KTA  17           // split-K first chunk
#define USTR 532          // ushorts per ustage row
#define NGRP 32
#define NBLK 8
#define RWORDS 264        // u32 words per payload row (528 bf16)

// workspace layout (bytes)
#define WS_AMATH 0                         // 544*260*4 = 565,760
#define WS_INIT  565760                    // 520*4 -> pad 2560
#define WS_PAY   568320                    // 2*32*8*264*4 = 540,672 (bf16 payload)
#define WS_FLG   (WS_PAY + 540672)         // 2*32*8*64B = 32,768 (flags, 64B stride)
#define WS_TOTAL (WS_FLG + 32768)

// LDS layout (bytes)
#define L_FRAG 0
#define L_UST  (NT*KT*64*8)                // 84,480
#define L_USL  (L_UST + 16*USTR*2)         // +17,024 = 101,504
#define L_SIG  (L_USL + 8*68*4)            // +2,176  = 103,680
#define LDS_TOTAL (L_SIG + 128)            // 103,808

__device__ __forceinline__ unsigned bfbits(float x) {
    unsigned u = __builtin_bit_cast(unsigned, x);
    unsigned r = u + 0x7FFFu + ((u >> 16) & 1u);
    return r >> 16;
}
__device__ __forceinline__ float bflo(u32t w) {
    return __builtin_bit_cast(float, w << 16);
}
__device__ __forceinline__ float bfhi(u32t w) {
    return __builtin_bit_cast(float, w & 0xffff0000u);
}

__global__ void prep_A(const float* __restrict__ logA, unsigned* __restrict__ AMATh) {
    __shared__ float red[4];
    __shared__ float srow[Qn];
    int row = blockIdx.x, tid = threadIdx.x;
    if (row >= Qn) {
        for (int c = tid; c < 260; c += 256) AMATh[(size_t)row*260 + c] = 0u;
        return;
    }
    float mx = -1e30f;
    for (int c = tid; c < Qn; c += 256) { float x = logA[(size_t)row*Qn + c]; srow[c] = x; mx = fmaxf(mx, x); }
#pragma unroll
    for (int o = 32; o > 0; o >>= 1) mx = fmaxf(mx, __shfl_xor(mx, o));
    if ((tid & 63) == 0) red[tid >> 6] = mx;
    __syncthreads();
    mx = fmaxf(fmaxf(red[0], red[1]), fmaxf(red[2], red[3]));
    __syncthreads();
    float sm = 0.f;
    for (int c = tid; c < Qn; c += 256) sm += __expf(srow[c] - mx);
#pragma unroll
    for (int o = 32; o > 0; o >>= 1) sm += __shfl_xor(sm, o);
    if ((tid & 63) == 0) red[tid >> 6] = sm;
    __syncthreads();
    float inv = 1.f / (red[0] + red[1] + red[2] + red[3]);
    for (int c2 = tid; c2 < 260; c2 += 256) {
        int c = 2*c2;
        float v0 = (c   < Qn) ? __expf(srow[c]   - mx) * inv : 0.f;
        float v1 = (c+1 < Qn) ? __expf(srow[c+1] - mx) * inv : 0.f;
        AMATh[(size_t)row*260 + c2] = bfbits(v0) | (bfbits(v1) << 16);
    }
}

__global__ void prep_init(const float* __restrict__ il, float* __restrict__ INITD) {
    __shared__ float red[4];
    __shared__ float srow[Qn];
    int tid = threadIdx.x;
    float mx = -1e30f;
    for (int c = tid; c < Qn; c += 256) { float x = il[c]; srow[c] = x; mx = fmaxf(mx, x); }
#pragma unroll
    for (int o = 32; o > 0; o >>= 1) mx = fmaxf(mx, __shfl_xor(mx, o));
    if ((tid & 63) == 0) red[tid >> 6] = mx;
    __syncthreads();
    mx = fmaxf(fmaxf(red[0], red[1]), fmaxf(red[2], red[3]));
    __syncthreads();
    float sm = 0.f;
    for (int c = tid; c < Qn; c += 256) sm += __expf(srow[c] - mx);
#pragma unroll
    for (int o = 32; o > 0; o >>= 1) sm += __shfl_xor(sm, o);
    if ((tid & 63) == 0) red[tid >> 6] = sm;
    __syncthreads();
    float inv = 1.f / (red[0] + red[1] + red[2] + red[3]);
    for (int c = tid; c < 520; c += 256)
        INITD[c] = (c < Qn) ? __expf(srow[c] - mx) * inv : 0.f;
}

__global__ void __launch_bounds__(256, 1)
hmm_fwd(const float* __restrict__ E, const unsigned* __restrict__ AMATh,
        const float* __restrict__ INITD, float* __restrict__ out,
        u32t* __restrict__ pay, u32t* __restrict__ flg)
{
    extern __shared__ char smem[];
    uint2* frag = (uint2*)(smem + L_FRAG);                    // [NT*KT*64]
    unsigned short* ustage = (unsigned short*)(smem + L_UST); // [16][USTR]
    u32t* ustage32 = (u32t*)ustage;
    float* usl  = (float*)(smem + L_USL);                     // [8][68]
    float* invs = (float*)(smem + L_SIG);                     // [8]
    float* lsig = invs + 8;                                   // [8]

    const int tid  = threadIdx.x;
    const int lane = tid & 63;
    const int wv   = tid >> 6;
    const int bid  = blockIdx.x;
    const int g    = bid & 31;
    const int j    = bid >> 5;
    const int b0   = g * 8;
    const int q0   = j * NSL;

    // ---- one-time: pack A column-slice into LDS as MFMA B-fragments ----
    for (int f = tid; f < NT*KT*64; f += 256) {
        int tile = f >> 6, l = f & 63;
        int nt = tile / KT, kt = tile - nt*KT;
        int col = q0 + nt*16 + (l & 15);
        int kb  = kt*16 + ((l >> 4) << 2);
        unsigned h[4];
#pragma unroll
        for (int i = 0; i < 4; ++i) {
            int pk_ = kb + i;
            int jr = pk_ / 66, rr = pk_ - jr*66;
            unsigned hv = 0;
            if (rr < 65 && col < QP) {
                int qrow = jr*65 + rr;
                unsigned w = AMATh[(size_t)qrow*260 + (col >> 1)];
                hv = (col & 1) ? (w >> 16) : (w & 0xffffu);
            }
            h[i] = hv;
        }
        uint2 pk;
        pk.x = h[0] | (h[1] << 16);
        pk.y = h[2] | (h[3] << 16);
        frag[f] = pk;
    }
    for (int i = tid; i < 16*(USTR/2); i += 256) ustage32[i] = 0u;
    __syncthreads();

    // ---- per-thread maps ----
    const int ntn = (wv == 0) ? 2 : 1;
    const int nts0 = wv;
    int eoff[2][4];
#pragma unroll
    for (int sl = 0; sl < 2; ++sl) {
#pragma unroll
        for (int r = 0; r < 4; ++r) {
            int nt  = sl ? 4 : nts0;
            int row = ((lane >> 4) << 2) + r;
            int col = nt*16 + (lane & 15);
            int q   = q0 + col;
            bool ok = (lane < 32) && (col < NSL) && (q < Qn) && (sl < ntn);
            eoff[sl][r] = ok ? ((b0 + row)*Qn + q) : -1;
        }
    }
    const int rrow = tid >> 5;     // reader row 0..7
    const int t32  = tid & 31;
    const int nw   = (t32 < 8) ? 9 : 8;   // payload u32 words per thread

    float llreg = 0.f;
    float lsr = 0.f;
    u32t w9[9];

    // payload/flag addressing helpers
    auto pay_base = [&](int slot) { return pay + ((size_t)slot*NGRP + g)*(8*RWORDS); };
    auto flg_idx  = [&](int slot, int jj) { return ((unsigned)(slot*NGRP + g)*NBLK + jj)*16; };

    // ---- writer: pack usl [8][66] (f32) -> bf16 payload + flag ----
    auto publish = [&](int s) {       // stores u_s, tag s+1, slot s&1
        __syncthreads();              // usl complete (and prior MFMA done)
        u32t* pb = pay_base(s & 1);
        for (int p = tid; p < 8*33; p += 256) {
            int row = p / 33, c2 = p - row*33;
            float a0 = usl[row*68 + 2*c2];
            float a1 = usl[row*68 + 2*c2 + 1];
            u32t pk = bfbits(a0) | (bfbits(a1) << 16);
            __hip_atomic_store(&pb[row*RWORDS + 33*j + c2], pk,
                               __ATOMIC_RELAXED, __HIP_MEMORY_SCOPE_AGENT);
        }
        __syncthreads();              // vmcnt(0) drain: payload at coherence point
        if (tid == 0)
            __hip_atomic_store(&flg[flg_idx(s & 1, j)], (u32t)(s + 1),
                               __ATOMIC_RELAXED, __HIP_MEMORY_SCOPE_AGENT);
    };

    auto poll_flags = [&](int s) {    // wait all 8 producers posted tag s (slot (s-1)&1)
        const u32t* fb = flg + flg_idx((s - 1) & 1, 0);
        unsigned want = (unsigned)s;
        while (true) {
            u32t fv = 0xffffffffu;
            if (lane < 8)
                fv = __hip_atomic_load(&fb[lane*16], __ATOMIC_RELAXED, __HIP_MEMORY_SCOPE_AGENT);
            if (__all(fv >= want)) break;
        }
    };

    auto bulk_reduce = [&](int s) {   // load row rrow payload, row-sum, invs/lsig
        const u32t* pb = pay_base((s - 1) & 1) + (size_t)rrow*RWORDS;
#pragma unroll
        for (int k = 0; k < 8; ++k)
            w9[k] = __hip_atomic_load(&pb[t32 + 32*k], __ATOMIC_RELAXED, __HIP_MEMORY_SCOPE_AGENT);
        w9[8] = (t32 < 8) ? __hip_atomic_load(&pb[256 + t32], __ATOMIC_RELAXED, __HIP_MEMORY_SCOPE_AGENT) : 0u;
        float sum = 0.f;
#pragma unroll
        for (int k = 0; k < 9; ++k) {
            if (k < nw) { sum += bflo(w9[k]) + bfhi(w9[k]); }
        }
#pragma unroll
        for (int o = 1; o < 32; o <<= 1) sum += __shfl_xor(sum, o);
        lsr = __logf(sum);
        llreg += lsr;
        if (t32 == 0) { invs[rrow] = 1.f / sum; lsig[rrow] = lsr; }
    };

    auto stage = [&]() {              // normalized bf16 -> ustage
        float iv = invs[rrow];
#pragma unroll
        for (int k = 0; k < 9; ++k) {
            if (k < nw) {
                int wi = (k < 8) ? (t32 + 32*k) : (256 + t32);
                u32t pk = bfbits(bflo(w9[k]) * iv) | (bfbits(bfhi(w9[k]) * iv) << 16);
                ustage32[rrow*(USTR/2) + wi] = pk;
            }
        }
    };

    auto emit_outputs = [&](int tOut) {
        if (t32 == 0 && j == 0)
            out[((size_t)(b0 + rrow)*Tn + tOut)*OQ + Qn] = llreg;
        float* orow = out + ((size_t)(b0 + rrow)*Tn + tOut)*OQ;
#pragma unroll
        for (int k = 0; k < 9; ++k) {
            if (k < nw) {
                int wi = (k < 8) ? (t32 + 32*k) : (256 + t32);
                int c0 = 2*wi;
#pragma unroll
                for (int h = 0; h < 2; ++h) {
                    int c = c0 + h;
                    int jr = c / 66, loc = c - jr*66;
                    if (jr == j && loc < 65) {
                        int q = q0 + loc;
                        if (q < Qn) {
                            float f = h ? bfhi(w9[k]) : bflo(w9[k]);
                            orow[q] = __logf(f) - lsr;
                        }
                    }
                }
            }
        }
    };

    // ---- t = 0 : u0 = max(E0,eps) * max(init,eps) -> usl -> publish ----
    for (int p = tid; p < 8*66; p += 256) {
        int row = p / 66, c = p - row*66;
        int q = q0 + c;
        float uv = 0.f;
        if (c < 65 && q < Qn)
            uv = fmaxf(E[(size_t)(b0+row)*Qn + q], EPSc) * fmaxf(INITD[q], EPSc);
        usl[row*68 + c] = uv;   // col 65 pad stays 0 forever after this
    }
    publish(0);

    // ---- main loop ----
    for (int s = 1; s < Tn; ++s) {
        // prefetch E_s (HBM latency hides under the poll)
        float ev[2][4];
        size_t ebase = (size_t)s * Bn * Qn;
#pragma unroll
        for (int sl = 0; sl < 2; ++sl)
#pragma unroll
            for (int r = 0; r < 4; ++r)
                ev[sl][r] = (eoff[sl][r] >= 0) ? E[ebase + eoff[sl][r]] : 0.f;

        poll_flags(s);
        bulk_reduce(s);
        __syncthreads();    // invs ready AND previous MFMA's ustage reads done
        stage();
        __syncthreads();    // ustage visible

        // MFMA: R = a_{s-1} (16xK, rows 8..15 zero) @ Aslice (KxN), split-K x2
        f32x4 a0a = {0.f,0.f,0.f,0.f}, a0b = {0.f,0.f,0.f,0.f};
        f32x4 a1a = {0.f,0.f,0.f,0.f}, a1b = {0.f,0.f,0.f,0.f};
        {
            const unsigned short* urow = ustage + (lane & 15)*USTR + ((lane >> 4) << 2);
            const uint2* f0 = frag + (size_t)(nts0*KT)*64 + lane;
            const uint2* f1 = frag + (size_t)(4*KT)*64 + lane;
#pragma unroll 2
            for (int kt = 0; kt < KTA; ++kt) {
                s16x4 af = __builtin_bit_cast(s16x4, *(const uint2*)(urow + kt*16));
                a0a = __builtin_amdgcn_mfma_f32_16x16x16bf16_1k(af, __builtin_bit_cast(s16x4, f0[kt*64]), a0a, 0, 0, 0);
                if (ntn == 2)
                    a1a = __builtin_amdgcn_mfma_f32_16x16x16bf16_1k(af, __builtin_bit_cast(s16x4, f1[kt*64]), a1a, 0, 0, 0);
                int k2 = kt + KTA;
                if (k2 < KT) {
                    s16x4 af2 = __builtin_bit_cast(s16x4, *(const uint2*)(urow + k2*16));
                    a0b = __builtin_amdgcn_mfma_f32_16x16x16bf16_1k(af2, __builtin_bit_cast(s16x4, f0[k2*64]), a0b, 0, 0, 0);
                    if (ntn == 2)
                        a1b = __builtin_amdgcn_mfma_f32_16x16x16bf16_1k(af2, __builtin_bit_cast(s16x4, f1[k2*64]), a1b, 0, 0, 0);
                }
            }
        }
        // epilogue: u_s = max(E,eps) * max(R,eps) -> usl
        if (lane < 32) {
#pragma unroll
            for (int r = 0; r < 4; ++r) {
                int row = ((lane >> 4) << 2) + r;
                {
                    int col = nts0*16 + (lane & 15);
                    if (col < NSL) {
                        float R = fmaxf(a0a[r] + a0b[r], EPSc);
                        int q = q0 + col;
                        usl[row*68 + col] = (q < Qn) ? fmaxf(ev[0][r], EPSc) * R : 0.f;
                    }
                }
                if (ntn == 2) {
                    int col = 64 + (lane & 15);
                    if (col < NSL) {
                        float R = fmaxf(a1a[r] + a1b[r], EPSc);
                        int q = q0 + col;
                        usl[row*68 + col] = (q < Qn) ? fmaxf(ev[1][r], EPSc) * R : 0.f;
                    }
                }
            }
        }
        publish(s);

        // off the inter-block critical path: log-outputs for t = s-1
        emit_outputs(s - 1);
    }

    // ---- tail: t = 511 ----
    poll_flags(Tn);
    bulk_reduce(Tn);
    emit_outputs(Tn - 1);
}

extern "C" void kernel_launch(void* const* d_in, const int* in_sizes, int n_in,
                              void* d_out, int out_size, void* d_ws, size_t ws_size,
                              hipStream_t stream) {
    (void)in_sizes; (void)n_in; (void)out_size;
    if (ws_size < (size_t)WS_TOTAL) return;

    const float* E    = (const float*)d_in[0];
    const float* logA = (const float*)d_in[1];
    const float* il   = (const float*)d_in[2];
    float* out = (float*)d_out;
    char*  ws  = (char*)d_ws;

    unsigned* AMATh = (unsigned*)(ws + WS_AMATH);
    float*    INITD = (float*)(ws + WS_INIT);
    u32t*     pay   = (u32t*)(ws + WS_PAY);
    u32t*     flgp  = (u32t*)(ws + WS_FLG);

    // flags MUST be zeroed every launch/replay (harness poisons ws to 0xAA;
    // leftover flags from a previous replay would satisfy polls with stale data)
    hipMemsetAsync(ws + WS_FLG, 0, 32768, stream);

    prep_A<<<544, 256, 0, stream>>>(logA, AMATh);
    prep_init<<<1, 256, 0, stream>>>(il, INITD);

    static_assert(LDS_TOTAL < 160*1024, "LDS budget");
    hipFuncSetAttribute(reinterpret_cast<const void*>(hmm_fwd),
                        hipFuncAttributeMaxDynamicSharedMemorySize, LDS_TOTAL);
    hmm_fwd<<<256, 256, LDS_TOTAL, stream>>>(E, AMATh, INITD, out, pay, flgp);
}